// Round 19
// baseline (974.911 us; speedup 1.0000x reference)
//
#include <hip/hip_runtime.h>
#include <hip/hip_fp16.h>

#define N_NODES 100000
#define N_EDGES 1600000
#define NL 4
#define NG 1024
#define ZS 68    // zstats LDS fp32 tile stride

typedef _Float16 f16x8 __attribute__((ext_vector_type(8)));
typedef float f32x4 __attribute__((ext_vector_type(4)));

// ---------------------------------------------------------------------------
// ws layout (floats):
//   A      @ 0        : N*64 fp32 (z2 at l=3, read by pool) -- ALIASED fp16
//                       mirror A16 (row-major, gather source). atom_embed +
//                       mm2(l<3) write A16; mm2(l=3) writes fp32.
//   B      @ 6.4M     : N*64 slot; z16 (fp16, row-major)
//   stats  @ 12.8M    : [4 x (cs 64 | M 4096) = 16640 | s2 64 | q2 64 |
//                        a1 128 | c1p 128 | w1t16 | w2t16]
//   ints   @ ...      : ptr[100001] deg[100000] csr[1.6M] bs[391]
// BN2 affine never materialized (pull/pool compute per-lane from s2/q2/g/b).
// pull block 0 zeroes ONLY [0,16640); s2/q2 zeroed by k_fin1 (r15 race fix).
// ---------------------------------------------------------------------------

__global__ void k_atom_embed(const int* __restrict__ x, const float* __restrict__ emb,
                             __half* __restrict__ h16) {
  int n = blockIdx.x * 4 + (threadIdx.x >> 6);
  int d = threadIdx.x & 63;
  const int* xr = x + n * 9;
  float acc = 0.f;
#pragma unroll
  for (int c = 0; c < 9; ++c) acc += emb[(c * 100 + xr[c]) * 64 + d];
  h16[(size_t)n * 64 + d] = __float2half(acc);
}

// ---------------- CSR build (once per call) --------------------------------
__global__ void k_hist(const int* __restrict__ ei, int* __restrict__ deg) {
  int e = blockIdx.x * 256 + threadIdx.x;
  if (e < N_EDGES) atomicAdd(&deg[ei[e]], 1);
}

__global__ void k_scan1(const int* __restrict__ deg, int* __restrict__ bs) {
  __shared__ int s[256];
  int g = blockIdx.x * 256 + threadIdx.x;
  int v = (g < N_NODES) ? deg[g] : 0;
  s[threadIdx.x] = v;
  __syncthreads();
  for (int o = 128; o > 0; o >>= 1) {
    if (threadIdx.x < o) s[threadIdx.x] += s[threadIdx.x + o];
    __syncthreads();
  }
  if (threadIdx.x == 0) bs[blockIdx.x] = s[0];
}

__global__ void k_scan2(int* __restrict__ bs, int nblk) {
  __shared__ int s[512];
  int tid = threadIdx.x;
  int v = (tid < nblk) ? bs[tid] : 0;
  s[tid] = v;
  __syncthreads();
  for (int o = 1; o < 512; o <<= 1) {
    int t = (tid >= o) ? s[tid - o] : 0;
    __syncthreads();
    s[tid] += t;
    __syncthreads();
  }
  if (tid < nblk) bs[tid] = s[tid] - v;  // exclusive
}

__global__ void k_scan3(int* __restrict__ deg, const int* __restrict__ bs,
                        int* __restrict__ ptr) {
  __shared__ int s[256];
  int tid = threadIdx.x;
  int g = blockIdx.x * 256 + tid;
  int v = (g < N_NODES) ? deg[g] : 0;
  s[tid] = v;
  __syncthreads();
  for (int o = 1; o < 256; o <<= 1) {
    int t = (tid >= o) ? s[tid - o] : 0;
    __syncthreads();
    s[tid] += t;
    __syncthreads();
  }
  if (g < N_NODES) {
    int val = bs[blockIdx.x] + s[tid] - v;
    ptr[g] = val;
    deg[g] = val;  // reuse deg as fill cursor
  }
  if (g == 0) ptr[N_NODES] = N_EDGES;
}

__global__ void k_fill(const int* __restrict__ ei, const int* __restrict__ ea,
                       int* __restrict__ cur, unsigned int* __restrict__ csr) {
  int e = blockIdx.x * 256 + threadIdx.x;
  if (e >= N_EDGES) return;
  int s = ei[e];
  unsigned int dst = (unsigned int)ei[N_EDGES + e];
  unsigned int b = (unsigned int)(ea[e * 3] | (ea[e * 3 + 1] << 3) | (ea[e * 3 + 2] << 6));
  int pos = atomicAdd(&cur[s], 1);
  csr[pos] = dst | (b << 17);
}

// ---------------- pull: 8 edges per pass-group, half8 lanes -----------------
// Lane = 8 dims (16B uint4 load); group g8 = l>>3 gathers its own edge ->
// 32 edges in flight per 4-deep pass (r18 half4: 16 -- the r17->r18 scaling
// law says edges-in-flight is the binding variable). Skeleton preserved:
// coalesced 64-lane csr read + shfl broadcast, uniform per-node loop.
// Reduce: shfl_xor(8,16,32); group 0 writes the row (8 lanes x 16B = 128B).
__global__ void __launch_bounds__(256)
k_pull(const __half* __restrict__ src, const unsigned int* __restrict__ csr,
       const int* __restrict__ ptr, const float* __restrict__ bond,
       const float* __restrict__ s2p, const float* __restrict__ q2p,
       const float* __restrict__ bng, const float* __restrict__ bnb,
       const float* __restrict__ epsp, int reluf,
       __half* __restrict__ z, float* __restrict__ stats0) {
  __shared__ float sb[1536];
  for (int i = threadIdx.x; i < 1536; i += 256) sb[i] = bond[i];
  const int wave = threadIdx.x >> 6, l = threadIdx.x & 63;
  const int g8 = l >> 3, hl = l & 7;
  const int d0 = hl * 8;  // this lane's dims: d0..d0+7
  const float ep1 = 1.0f + epsp[0];
  float aA[8], cC[8];
#pragma unroll
  for (int dd = 0; dd < 8; ++dd) { aA[dd] = 1.f; cC[dd] = 0.f; }
  if (reluf) {
    const float inv = 1.0f / (float)N_NODES;
#pragma unroll
    for (int dd = 0; dd < 8; ++dd) {
      float m = s2p[d0 + dd] * inv;
      float r = rsqrtf(q2p[d0 + dd] * inv - m * m + 1e-5f);
      aA[dd] = bng[d0 + dd] * r;
      cC[dd] = fmaf(-m, aA[dd], bnb[d0 + dd]);
    }
  }
  if (blockIdx.x == 0)
    for (int i = threadIdx.x; i < 16640; i += 256) stats0[i] = 0.f;  // cs/M ONLY
  __syncthreads();
  const int n0 = blockIdx.x * 32 + wave * 8;
#pragma unroll
  for (int ii = 0; ii < 8; ++ii) {
    const int n = n0 + ii;
    const int p0 = ptr[n], p1 = ptr[n + 1];
    float acc[8] = {0.f, 0.f, 0.f, 0.f, 0.f, 0.f, 0.f, 0.f};
    for (int base = p0; base < p1; base += 64) {
      const int cnt = min(64, p1 - base);
      unsigned int mypk = (l < cnt) ? csr[base + l] : 0u;
      int i = 0;
      for (; i + 32 <= cnt; i += 32) {  // 4 deep x 8 groups = 32 edges
        unsigned int pk[4];
        uint4 hv[4];
#pragma unroll
        for (int u = 0; u < 4; ++u) pk[u] = __shfl(mypk, i + 8 * u + g8);
#pragma unroll
        for (int u = 0; u < 4; ++u)
          hv[u] = *(const uint4*)&src[(size_t)(pk[u] & 0x1FFFFu) * 64 + d0];
#pragma unroll
        for (int u = 0; u < 4; ++u) {
          const __half* hp = (const __half*)&hv[u];
          const unsigned int b = pk[u] >> 17;
          const float* e0p = &sb[(b & 7) * 64 + d0];
          const float* e1p = &sb[(((b >> 3) & 7) + 8) * 64 + d0];
          const float* e2p = &sb[((b >> 6) + 16) * 64 + d0];
#pragma unroll
          for (int dd = 0; dd < 8; ++dd) {
            float v = __half2float(hp[dd]);
            if (reluf) v = fmaxf(fmaf(v, aA[dd], cC[dd]), 0.f);
            acc[dd] += fmaxf(v + e0p[dd] + e1p[dd] + e2p[dd], 0.f);
          }
        }
      }
      for (; i + 16 <= cnt; i += 16) {  // 2 deep x 8 groups = 16 edges
        unsigned int pk[2];
        uint4 hv[2];
#pragma unroll
        for (int u = 0; u < 2; ++u) pk[u] = __shfl(mypk, i + 8 * u + g8);
#pragma unroll
        for (int u = 0; u < 2; ++u)
          hv[u] = *(const uint4*)&src[(size_t)(pk[u] & 0x1FFFFu) * 64 + d0];
#pragma unroll
        for (int u = 0; u < 2; ++u) {
          const __half* hp = (const __half*)&hv[u];
          const unsigned int b = pk[u] >> 17;
          const float* e0p = &sb[(b & 7) * 64 + d0];
          const float* e1p = &sb[(((b >> 3) & 7) + 8) * 64 + d0];
          const float* e2p = &sb[((b >> 6) + 16) * 64 + d0];
#pragma unroll
          for (int dd = 0; dd < 8; ++dd) {
            float v = __half2float(hp[dd]);
            if (reluf) v = fmaxf(fmaf(v, aA[dd], cC[dd]), 0.f);
            acc[dd] += fmaxf(v + e0p[dd] + e1p[dd] + e2p[dd], 0.f);
          }
        }
      }
      for (; i < cnt; i += 8) {  // tail: each group one edge, predicated
        const int e = i + g8;
        unsigned int pks = __shfl(mypk, (e < 64) ? e : 0);
        if (e < cnt) {
          uint4 hv = *(const uint4*)&src[(size_t)(pks & 0x1FFFFu) * 64 + d0];
          const __half* hp = (const __half*)&hv;
          const unsigned int b = pks >> 17;
          const float* e0p = &sb[(b & 7) * 64 + d0];
          const float* e1p = &sb[(((b >> 3) & 7) + 8) * 64 + d0];
          const float* e2p = &sb[((b >> 6) + 16) * 64 + d0];
#pragma unroll
          for (int dd = 0; dd < 8; ++dd) {
            float v = __half2float(hp[dd]);
            if (reluf) v = fmaxf(fmaf(v, aA[dd], cC[dd]), 0.f);
            acc[dd] += fmaxf(v + e0p[dd] + e1p[dd] + e2p[dd], 0.f);
          }
        }
      }
    }
#pragma unroll
    for (int dd = 0; dd < 8; ++dd) {
      acc[dd] += __shfl_xor(acc[dd], 8);
      acc[dd] += __shfl_xor(acc[dd], 16);
      acc[dd] += __shfl_xor(acc[dd], 32);
    }
    if (g8 == 0) {
      uint4 ow = *(const uint4*)&src[(size_t)n * 64 + d0];
      const __half* op = (const __half*)&ow;
      __half hv[8];
#pragma unroll
      for (int dd = 0; dd < 8; ++dd) {
        float o = __half2float(op[dd]);
        if (reluf) o = fmaxf(fmaf(o, aA[dd], cC[dd]), 0.f);
        hv[dd] = __float2half(fmaf(ep1, o, acc[dd]));
      }
      *(uint4*)&z[(size_t)n * 64 + d0] = *(uint4*)hv;
    }
  }
}

// ---------------- BN1 moments from z16: colsum, M = z^T z -------------------
__global__ void __launch_bounds__(256)
k_zstats(const __half* __restrict__ z, float* __restrict__ stats) {
  __shared__ __align__(16) float zl[2][64 * ZS];
  __shared__ float red[256];
  const int tid = threadIdx.x;
  const int wave = tid >> 6, d = tid & 63;
  const int ar = (tid >> 4) * 4, bc = (tid & 15) * 4;
  const int nr = tid >> 4, kc4 = (tid & 15) << 2;
  uint2 pf[4];

#define ZS_ISSUE(t)                                                           \
  {                                                                           \
    const int nb_ = (blockIdx.x * 4 + (t)) * 64;                              \
    const int nlim_ = N_NODES - nb_;                                          \
    _Pragma("unroll") for (int u = 0; u < 4; ++u) {                           \
      const int n_ = nr + u * 16;                                             \
      pf[u] = make_uint2(0u, 0u);                                             \
      if (n_ < nlim_) pf[u] = *(const uint2*)&z[(size_t)(nb_ + n_) * 64 + kc4]; \
    }                                                                         \
  }
#define ZS_STORE(buf)                                                         \
  {                                                                           \
    _Pragma("unroll") for (int u = 0; u < 4; ++u) {                           \
      const __half* hp_ = (const __half*)&pf[u];                              \
      float4 f_ = make_float4(__half2float(hp_[0]), __half2float(hp_[1]),     \
                              __half2float(hp_[2]), __half2float(hp_[3]));    \
      *(float4*)&zl[buf][(nr + u * 16) * ZS + kc4] = f_;                      \
    }                                                                         \
  }

  ZS_ISSUE(0);
  ZS_STORE(0);
  __syncthreads();

  float accS = 0.f;
  float m00 = 0.f, m01 = 0.f, m02 = 0.f, m03 = 0.f;
  float m10 = 0.f, m11 = 0.f, m12 = 0.f, m13 = 0.f;
  float m20 = 0.f, m21 = 0.f, m22 = 0.f, m23 = 0.f;
  float m30 = 0.f, m31 = 0.f, m32 = 0.f, m33 = 0.f;
  for (int t = 0; t < 4; ++t) {
    const int cur = t & 1;
    if (t < 3) ZS_ISSUE(t + 1);
#pragma unroll
    for (int ii = 0; ii < 16; ++ii) accS += zl[cur][(wave * 16 + ii) * ZS + d];
#pragma unroll 4
    for (int n = 0; n < 64; ++n) {
      const float4 a = *(const float4*)&zl[cur][n * ZS + ar];
      const float4 b = *(const float4*)&zl[cur][n * ZS + bc];
      m00 = fmaf(a.x, b.x, m00); m01 = fmaf(a.x, b.y, m01); m02 = fmaf(a.x, b.z, m02); m03 = fmaf(a.x, b.w, m03);
      m10 = fmaf(a.y, b.x, m10); m11 = fmaf(a.y, b.y, m11); m12 = fmaf(a.y, b.z, m12); m13 = fmaf(a.y, b.w, m13);
      m20 = fmaf(a.z, b.x, m20); m21 = fmaf(a.z, b.y, m21); m22 = fmaf(a.z, b.z, m22); m23 = fmaf(a.z, b.w, m23);
      m30 = fmaf(a.w, b.x, m30); m31 = fmaf(a.w, b.y, m31); m32 = fmaf(a.w, b.z, m32); m33 = fmaf(a.w, b.w, m33);
    }
    __syncthreads();
    if (t < 3) {
      ZS_STORE(cur ^ 1);
      __syncthreads();
    }
  }
  float* copy = stats + (blockIdx.x & 3) * 4160;  // [cs 64 | M 4096]
  red[tid] = accS;
  __syncthreads();
  if (tid < 64)
    atomicAdd(&copy[tid], red[tid] + red[tid + 64] + red[tid + 128] + red[tid + 192]);
  float* M = copy + 64;
  atomicAdd(&M[(ar + 0) * 64 + bc + 0], m00); atomicAdd(&M[(ar + 0) * 64 + bc + 1], m01);
  atomicAdd(&M[(ar + 0) * 64 + bc + 2], m02); atomicAdd(&M[(ar + 0) * 64 + bc + 3], m03);
  atomicAdd(&M[(ar + 1) * 64 + bc + 0], m10); atomicAdd(&M[(ar + 1) * 64 + bc + 1], m11);
  atomicAdd(&M[(ar + 1) * 64 + bc + 2], m12); atomicAdd(&M[(ar + 1) * 64 + bc + 3], m13);
  atomicAdd(&M[(ar + 2) * 64 + bc + 0], m20); atomicAdd(&M[(ar + 2) * 64 + bc + 1], m21);
  atomicAdd(&M[(ar + 2) * 64 + bc + 2], m22); atomicAdd(&M[(ar + 2) * 64 + bc + 3], m23);
  atomicAdd(&M[(ar + 3) * 64 + bc + 0], m30); atomicAdd(&M[(ar + 3) * 64 + bc + 1], m31);
  atomicAdd(&M[(ar + 3) * 64 + bc + 2], m32); atomicAdd(&M[(ar + 3) * 64 + bc + 3], m33);
#undef ZS_ISSUE
#undef ZS_STORE
}

// BN1 params + fp16 weight tables, parallel over 8 blocks. Block 0 zeroes
// s2/q2 (order: after pull reads them, before mm2 accumulates).
__global__ void __launch_bounds__(128)
k_fin1(const float* __restrict__ stats,
       const float* __restrict__ W1, const float* __restrict__ W2,
       const float* __restrict__ g1, const float* __restrict__ be1,
       float* __restrict__ a1, float* __restrict__ c1p,
       __half* __restrict__ w1t16, __half* __restrict__ w2t16,
       float* __restrict__ s2z, float* __restrict__ q2z) {
  __shared__ float Ml[4096];
  __shared__ float csl[64];
  const int tid = threadIdx.x, blk = blockIdx.x;
  if (blk == 0 && tid < 64) { s2z[tid] = 0.f; q2z[tid] = 0.f; }
  for (int i = tid; i < 4096; i += 128)
    Ml[i] = stats[64 + i] + stats[4160 + 64 + i] + stats[8320 + 64 + i] + stats[12480 + 64 + i];
  if (tid < 64) csl[tid] = stats[tid] + stats[4160 + tid] + stats[8320 + tid] + stats[12480 + tid];
  for (int i = blk * 1024 + tid; i < (blk + 1) * 1024; i += 128) {
    int k = i >> 6, jj = i & 63;
    w2t16[jj * 128 + k] = __float2half(W2[i]);
  }
  __syncthreads();
  const int j = blk * 16 + (tid >> 3), a = tid & 7;
  float wcol[64];
#pragma unroll
  for (int k = 0; k < 64; ++k) wcol[k] = W1[k * 128 + j];
#pragma unroll
  for (int kk = 0; kk < 8; ++kk)
    w1t16[j * 64 + a * 8 + kk] = __float2half(wcol[a * 8 + kk]);
  float m0 = 0.f;
#pragma unroll
  for (int kk = 0; kk < 8; ++kk)
    m0 = fmaf(csl[a * 8 + kk], wcol[a * 8 + kk], m0);
  float q = 0.f;
#pragma unroll
  for (int s = 0; s < 8; ++s) {
    const int ka = a + 8 * s;
    const float4* mr = (const float4*)&Ml[ka * 64];
    float t = 0.f;
#pragma unroll
    for (int kb = 0; kb < 16; ++kb) {
      float4 m = mr[kb];
      t = fmaf(m.x, wcol[kb * 4 + 0], t);
      t = fmaf(m.y, wcol[kb * 4 + 1], t);
      t = fmaf(m.z, wcol[kb * 4 + 2], t);
      t = fmaf(m.w, wcol[kb * 4 + 3], t);
    }
    q = fmaf(wcol[ka], t, q);
  }
  q += __shfl_xor(q, 1); q += __shfl_xor(q, 2); q += __shfl_xor(q, 4);
  m0 += __shfl_xor(m0, 1); m0 += __shfl_xor(m0, 2); m0 += __shfl_xor(m0, 4);
  if (a == 0) {
    m0 *= (1.0f / (float)N_NODES);
    float var = q * (1.0f / (float)N_NODES) - m0 * m0;
    float r = rsqrtf(var + 1e-5f);
    float A = g1[j] * r;
    a1[j] = A;
    c1p[j] = fmaf(-m0, A, be1[j]);
  }
}

// ---------------- fused MLP on MFMA (v_mfma_f32_16x16x32_f16) ---------------
__global__ void __launch_bounds__(256)
k_mm2(const __half* __restrict__ z16, const __half* __restrict__ w1t,
      const float* __restrict__ a1, const float* __restrict__ c1p,
      const __half* __restrict__ w2t, const float* __restrict__ b2,
      float* __restrict__ zout, __half* __restrict__ zout16, int tofp16,
      float* __restrict__ s2, float* __restrict__ q2) {
  __shared__ __align__(16) float sm[7040];           // 28.2 KB
  __half* z16l = (__half*)sm;                        // [64][72]
  __half* w1tl = (__half*)(sm + 2304);               // [128][72]
  __half* z1h = (__half*)sm;                         // [64][136] phase B overlay
  __half* w2tl = (__half*)(sm + 4352);               // [64][72]
  float* ss = sm + 6912;
  float* sq = sm + 6976;
  const int tid = threadIdx.x;
  const int nb = blockIdx.x * 64;
  const int nlim = N_NODES - nb;
  const int wv = tid >> 6, l = tid & 63;
  const int lrow = l & 15, lk = l >> 4;
  if (tid < 128) sm[6912 + tid] = 0.f;
  {
    int row = tid >> 2, seg = (tid & 3) * 16;
#pragma unroll
    for (int c = 0; c < 4; ++c) {
      uint2 v = make_uint2(0u, 0u);
      if (row < nlim) v = *(const uint2*)&z16[(size_t)(nb + row) * 64 + seg + c * 4];
      *(uint2*)&z16l[row * 72 + seg + c * 4] = v;
    }
  }
  {
    int row = tid >> 1, seg = (tid & 1) * 32;
#pragma unroll
    for (int c = 0; c < 8; ++c)
      *(uint2*)&w1tl[row * 72 + seg + c * 4] = *(const uint2*)&w1t[row * 64 + seg + c * 4];
  }
  __syncthreads();

  f32x4 acc[8];
#pragma unroll
  for (int jt = 0; jt < 8; ++jt) {
    f32x4 zr = {0.f, 0.f, 0.f, 0.f};
    acc[jt] = zr;
  }
  const f16x8 af0 = *(const f16x8*)&z16l[(16 * wv + lrow) * 72 + lk * 8];
  const f16x8 af1 = *(const f16x8*)&z16l[(16 * wv + lrow) * 72 + 32 + lk * 8];
#pragma unroll
  for (int jt = 0; jt < 8; ++jt) {
    const f16x8 b0 = *(const f16x8*)&w1tl[(lrow + 16 * jt) * 72 + lk * 8];
    const f16x8 b1 = *(const f16x8*)&w1tl[(lrow + 16 * jt) * 72 + 32 + lk * 8];
    acc[jt] = __builtin_amdgcn_mfma_f32_16x16x32_f16(af0, b0, acc[jt], 0, 0, 0);
    acc[jt] = __builtin_amdgcn_mfma_f32_16x16x32_f16(af1, b1, acc[jt], 0, 0, 0);
  }
  __syncthreads();  // z16l / w1tl reads complete; safe to overlay

#pragma unroll
  for (int jt = 0; jt < 8; ++jt) {
    const int col = lrow + 16 * jt;
    const float a = a1[col], cc = c1p[col];
#pragma unroll
    for (int r = 0; r < 4; ++r) {
      const int rl = 16 * wv + lk * 4 + r;
      float v = fmaxf(fmaf(acc[jt][r], a, cc), 0.f);
      z1h[rl * 136 + col] = __float2half(v);
    }
  }
  {
    int row = tid >> 2, seg = (tid & 3) * 16;
#pragma unroll
    for (int c = 0; c < 4; ++c)
      *(uint2*)&w2tl[row * 72 + seg + c * 4] = *(const uint2*)&w2t[row * 128 + seg + c * 4];
  }
  __syncthreads();

  f32x4 accB[4];
#pragma unroll
  for (int jt = 0; jt < 4; ++jt) {
    const float bb = b2[lrow + 16 * jt];
    f32x4 t = {bb, bb, bb, bb};
    accB[jt] = t;
  }
#pragma unroll
  for (int h = 0; h < 2; ++h) {
    if (h == 1) {
      __syncthreads();
      int row = tid >> 2, seg = (tid & 3) * 16;
#pragma unroll
      for (int c = 0; c < 4; ++c)
        *(uint2*)&w2tl[row * 72 + seg + c * 4] = *(const uint2*)&w2t[row * 128 + 64 + seg + c * 4];
      __syncthreads();
    }
#pragma unroll
    for (int kb = 0; kb < 2; ++kb) {
      const f16x8 afB = *(const f16x8*)&z1h[(16 * wv + lrow) * 136 + h * 64 + kb * 32 + lk * 8];
#pragma unroll
      for (int jt = 0; jt < 4; ++jt) {
        const f16x8 bfB = *(const f16x8*)&w2tl[(lrow + 16 * jt) * 72 + kb * 32 + lk * 8];
        accB[jt] = __builtin_amdgcn_mfma_f32_16x16x32_f16(afB, bfB, accB[jt], 0, 0, 0);
      }
    }
  }
  // epilogue: write z2 (fp16 l<3 / fp32 l=3) + stats
#pragma unroll
  for (int jt = 0; jt < 4; ++jt) {
    const int col = lrow + 16 * jt;
    float s = 0.f, q = 0.f;
#pragma unroll
    for (int r = 0; r < 4; ++r) {
      const int rl = 16 * wv + lk * 4 + r;
      if (rl < nlim) {
        const float v = accB[jt][r];
        if (tofp16) zout16[(size_t)(nb + rl) * 64 + col] = __float2half(v);
        else zout[(size_t)(nb + rl) * 64 + col] = v;
        s += v;
        q = fmaf(v, v, q);
      }
    }
    atomicAdd(&ss[col], s);
    atomicAdd(&sq[col], q);
  }
  __syncthreads();
  if (tid < 64) {
    atomicAdd(&s2[tid], ss[tid]);
    atomicAdd(&q2[tid], sq[tid]);
  }
}

// ---------------- pool: batch sorted; per-lane BN2 affine; zero atomics ----
__global__ void __launch_bounds__(256)
k_pool(const float* __restrict__ z2, const float* __restrict__ s2p,
       const float* __restrict__ q2p, const float* __restrict__ bng,
       const float* __restrict__ bnb, const int* __restrict__ batch,
       float* __restrict__ out) {
  int g = blockIdx.x * 4 + (threadIdx.x >> 6);
  int d = threadIdx.x & 63;
  const float inv = 1.0f / (float)N_NODES;
  float m = s2p[d] * inv;
  float vv = q2p[d] * inv - m * m;
  float r = rsqrtf(vv + 1e-5f);
  float a2 = bng[d] * r;
  float c2 = fmaf(-m, a2, bnb[d]);
  int a = 0, b = N_NODES;
  while (a < b) { int mm = (a + b) >> 1; if (batch[mm] < g) a = mm + 1; else b = mm; }
  const int lo = a;
  b = N_NODES;
  while (a < b) { int mm = (a + b) >> 1; if (batch[mm] < g + 1) a = mm + 1; else b = mm; }
  const int hi = a;
  float s0 = 0.f, s1 = 0.f, s2r = 0.f, s3 = 0.f;
  int n = lo;
  for (; n + 4 <= hi; n += 4) {
    s0 += z2[(size_t)(n + 0) * 64 + d];
    s1 += z2[(size_t)(n + 1) * 64 + d];
    s2r += z2[(size_t)(n + 2) * 64 + d];
    s3 += z2[(size_t)(n + 3) * 64 + d];
  }
  for (; n < hi; ++n) s0 += z2[(size_t)n * 64 + d];
  float S = (s0 + s1) + (s2r + s3);
  float cntf = (float)(hi - lo);
  out[g * 64 + d] = fmaf(S, a2, cntf * c2) / (cntf + 1e-9f);
}

extern "C" void kernel_launch(void* const* d_in, const int* in_sizes, int n_in,
                              void* d_out, int out_size, void* d_ws, size_t ws_size,
                              hipStream_t stream) {
  const int* x = (const int*)d_in[0];
  const int* ea = (const int*)d_in[1];
  const int* ei = (const int*)d_in[2];
  const int* batch = (const int*)d_in[3];
  const float* atom_emb = (const float*)d_in[4];
  const float* bond_emb = (const float*)d_in[5];
  const float* W1 = (const float*)d_in[6];
  const float* g1 = (const float*)d_in[8];
  const float* be1 = (const float*)d_in[9];
  const float* W2 = (const float*)d_in[10];
  const float* b2 = (const float*)d_in[11];
  const float* eps = (const float*)d_in[12];
  const float* bn_g = (const float*)d_in[13];
  const float* bn_b = (const float*)d_in[14];

  float* w = (float*)d_ws;
  float* A = w;                                 // fp32 z2 (layer 3 only)
  __half* A16 = (__half*)w;                     // row-major fp16 mirror
  float* B = w + (size_t)N_NODES * 64;
  __half* B16 = (__half*)B;
  float* stats = B + (size_t)N_NODES * 64;      // 4x(cs|M) = 16640
  float* s2 = stats + 16640;
  float* q2 = stats + 16704;
  float* a1 = stats + 16768;
  float* c1p = stats + 16896;
  __half* w1t16 = (__half*)(stats + 17024);     // 8192 halves
  __half* w2t16 = (__half*)(stats + 21120);     // 8192 halves
  int* ptr = (int*)(stats + 25216);             // 100001
  int* deg = ptr + (N_NODES + 1);               // 100000
  unsigned int* csr = (unsigned int*)(deg + N_NODES);  // 1.6M
  int* bs = (int*)(csr + N_EDGES);              // 391

  const int NBLK = (N_NODES + 255) / 256;   // 391
  const int NTILE = (N_NODES + 63) / 64;    // 1563
  const int NPULL = N_NODES / 32;           // 3125 (exact)
  const int NZ = NBLK;                      // 391

  hipMemsetAsync(deg, 0, N_NODES * sizeof(int), stream);

  k_atom_embed<<<N_NODES / 4, 256, 0, stream>>>(x, atom_emb, A16);

  // CSR build (once; reused across all 4 layers)
  k_hist<<<(N_EDGES + 255) / 256, 256, 0, stream>>>(ei, deg);
  k_scan1<<<NBLK, 256, 0, stream>>>(deg, bs);
  k_scan2<<<1, 512, 0, stream>>>(bs, NBLK);
  k_scan3<<<NBLK, 256, 0, stream>>>(deg, bs, ptr);
  k_fill<<<(N_EDGES + 255) / 256, 256, 0, stream>>>(ei, ea, deg, csr);

  for (int l = 0; l < NL; ++l) {
    k_pull<<<NPULL, 256, 0, stream>>>(
        A16, csr, ptr, bond_emb + (size_t)l * 1536, s2, q2,
        bn_g + (l > 0 ? (l - 1) * 64 : 0), bn_b + (l > 0 ? (l - 1) * 64 : 0),
        eps + l, (l > 0) ? 1 : 0, B16, stats);
    k_zstats<<<NZ, 256, 0, stream>>>(B16, stats);
    k_fin1<<<8, 128, 0, stream>>>(stats, W1 + (size_t)l * 8192, W2 + (size_t)l * 8192,
                                  g1 + l * 128, be1 + l * 128, a1, c1p, w1t16, w2t16,
                                  s2, q2);
    k_mm2<<<NTILE, 256, 0, stream>>>(
        B16, w1t16, a1, c1p, w2t16, b2 + l * 64,
        A, A16, (l < NL - 1) ? 1 : 0, s2, q2);
  }
  k_pool<<<NG / 4, 256, 0, stream>>>(A, s2, q2, bn_g + 3 * 64, bn_b + 3 * 64,
                                     batch, (float*)d_out);
}

// Round 20
// 902.497 us; speedup vs baseline: 1.0802x; 1.0802x over previous
//
#include <hip/hip_runtime.h>
#include <hip/hip_fp16.h>

#define N_NODES 100000
#define N_EDGES 1600000
#define NL 4
#define NG 1024
#define ZS 68    // zstats LDS fp32 tile stride

typedef _Float16 f16x8 __attribute__((ext_vector_type(8)));
typedef float f32x4 __attribute__((ext_vector_type(4)));

// ---------------------------------------------------------------------------
// ws layout (floats):
//   A      @ 0        : N*64 fp32 (z2 at l=3, read by pool) -- ALIASED fp16
//                       mirror A16 (row-major, gather source). atom_embed +
//                       mm2(l<3) write A16; mm2(l=3) writes fp32.
//   B      @ 6.4M     : N*64 slot; z16 (fp16, row-major)
//   stats  @ 12.8M    : [4 x (cs 64 | M 4096) = 16640 | s2 64 | q2 64 |
//                        a1 128 | c1p 128 | w1t16 | w2t16]
//   ints   @ ...      : ptr[100001] deg[100000] csr[1.6M] bs[391]
// BN2 affine never materialized (pull/pool compute per-lane from s2/q2/g/b).
// pull block 0 zeroes ONLY [0,16640); s2/q2 zeroed by k_fin1 (r15 race fix).
// r19 LESSON: half8 pull regressed (scalar LDS bond reads at lane-stride 8
// floats -> 8-way bank conflict, 4.5M cycles). half4 (float4 LDS reads,
// conflict-free) is the measured optimum -- reverted here.
// ---------------------------------------------------------------------------

__global__ void k_atom_embed(const int* __restrict__ x, const float* __restrict__ emb,
                             __half* __restrict__ h16) {
  int n = blockIdx.x * 4 + (threadIdx.x >> 6);
  int d = threadIdx.x & 63;
  const int* xr = x + n * 9;
  float acc = 0.f;
#pragma unroll
  for (int c = 0; c < 9; ++c) acc += emb[(c * 100 + xr[c]) * 64 + d];
  h16[(size_t)n * 64 + d] = __float2half(acc);
}

// ---------------- CSR build (once per call) --------------------------------
__global__ void k_hist(const int* __restrict__ ei, int* __restrict__ deg) {
  int e = blockIdx.x * 256 + threadIdx.x;
  if (e < N_EDGES) atomicAdd(&deg[ei[e]], 1);
}

__global__ void k_scan1(const int* __restrict__ deg, int* __restrict__ bs) {
  __shared__ int s[256];
  int g = blockIdx.x * 256 + threadIdx.x;
  int v = (g < N_NODES) ? deg[g] : 0;
  s[threadIdx.x] = v;
  __syncthreads();
  for (int o = 128; o > 0; o >>= 1) {
    if (threadIdx.x < o) s[threadIdx.x] += s[threadIdx.x + o];
    __syncthreads();
  }
  if (threadIdx.x == 0) bs[blockIdx.x] = s[0];
}

__global__ void k_scan2(int* __restrict__ bs, int nblk) {
  __shared__ int s[512];
  int tid = threadIdx.x;
  int v = (tid < nblk) ? bs[tid] : 0;
  s[tid] = v;
  __syncthreads();
  for (int o = 1; o < 512; o <<= 1) {
    int t = (tid >= o) ? s[tid - o] : 0;
    __syncthreads();
    s[tid] += t;
    __syncthreads();
  }
  if (tid < nblk) bs[tid] = s[tid] - v;  // exclusive
}

__global__ void k_scan3(int* __restrict__ deg, const int* __restrict__ bs,
                        int* __restrict__ ptr) {
  __shared__ int s[256];
  int tid = threadIdx.x;
  int g = blockIdx.x * 256 + tid;
  int v = (g < N_NODES) ? deg[g] : 0;
  s[tid] = v;
  __syncthreads();
  for (int o = 1; o < 256; o <<= 1) {
    int t = (tid >= o) ? s[tid - o] : 0;
    __syncthreads();
    s[tid] += t;
    __syncthreads();
  }
  if (g < N_NODES) {
    int val = bs[blockIdx.x] + s[tid] - v;
    ptr[g] = val;
    deg[g] = val;  // reuse deg as fill cursor
  }
  if (g == 0) ptr[N_NODES] = N_EDGES;
}

__global__ void k_fill(const int* __restrict__ ei, const int* __restrict__ ea,
                       int* __restrict__ cur, unsigned int* __restrict__ csr) {
  int e = blockIdx.x * 256 + threadIdx.x;
  if (e >= N_EDGES) return;
  int s = ei[e];
  unsigned int dst = (unsigned int)ei[N_EDGES + e];
  unsigned int b = (unsigned int)(ea[e * 3] | (ea[e * 3 + 1] << 3) | (ea[e * 3 + 2] << 6));
  int pos = atomicAdd(&cur[s], 1);
  csr[pos] = dst | (b << 17);
}

// ---------------- pull: 4 edges per wave-pass, half4 lanes (r18 optimum) ----
// Lane = 4 dims (8B load); quad q = l>>4 gathers its own edge -> 16 edges per
// 4-deep pass. Coalesced 64-lane csr read + shfl broadcast, uniform per-node
// loop. Reduce: shfl_xor(16,32); quad 0 writes the row (16 x 8B = 128B).
__global__ void __launch_bounds__(256)
k_pull(const __half* __restrict__ src, const unsigned int* __restrict__ csr,
       const int* __restrict__ ptr, const float* __restrict__ bond,
       const float* __restrict__ s2p, const float* __restrict__ q2p,
       const float* __restrict__ bng, const float* __restrict__ bnb,
       const float* __restrict__ epsp, int reluf,
       __half* __restrict__ z, float* __restrict__ stats0) {
  __shared__ float sb[1536];
  for (int i = threadIdx.x; i < 1536; i += 256) sb[i] = bond[i];
  const int wave = threadIdx.x >> 6, l = threadIdx.x & 63;
  const int q = l >> 4, hl = l & 15;
  const int d0 = hl * 4;  // this lane's dims: d0..d0+3
  const float ep1 = 1.0f + epsp[0];
  float aA[4] = {1.f, 1.f, 1.f, 1.f}, cC[4] = {0.f, 0.f, 0.f, 0.f};
  if (reluf) {
    const float inv = 1.0f / (float)N_NODES;
#pragma unroll
    for (int dd = 0; dd < 4; ++dd) {
      float m = s2p[d0 + dd] * inv;
      float r = rsqrtf(q2p[d0 + dd] * inv - m * m + 1e-5f);
      aA[dd] = bng[d0 + dd] * r;
      cC[dd] = fmaf(-m, aA[dd], bnb[d0 + dd]);
    }
  }
  if (blockIdx.x == 0)
    for (int i = threadIdx.x; i < 16640; i += 256) stats0[i] = 0.f;  // cs/M ONLY
  __syncthreads();
  const int n0 = blockIdx.x * 32 + wave * 8;
#pragma unroll
  for (int ii = 0; ii < 8; ++ii) {
    const int n = n0 + ii;
    const int p0 = ptr[n], p1 = ptr[n + 1];
    float acc[4] = {0.f, 0.f, 0.f, 0.f};
    for (int base = p0; base < p1; base += 64) {
      const int cnt = min(64, p1 - base);
      unsigned int mypk = (l < cnt) ? csr[base + l] : 0u;
      int i = 0;
      for (; i + 16 <= cnt; i += 16) {  // 4 groups x 4 quads = 16 edges
        unsigned int pk[4];
        uint2 hv[4];
#pragma unroll
        for (int u = 0; u < 4; ++u) pk[u] = __shfl(mypk, i + 4 * u + q);
#pragma unroll
        for (int u = 0; u < 4; ++u)
          hv[u] = *(const uint2*)&src[(size_t)(pk[u] & 0x1FFFFu) * 64 + d0];
#pragma unroll
        for (int u = 0; u < 4; ++u) {
          const __half* hp = (const __half*)&hv[u];
          const unsigned int b = pk[u] >> 17;
          const float4 e0 = *(const float4*)&sb[(b & 7) * 64 + d0];
          const float4 e1 = *(const float4*)&sb[(((b >> 3) & 7) + 8) * 64 + d0];
          const float4 e2 = *(const float4*)&sb[((b >> 6) + 16) * 64 + d0];
          const float* e0p = (const float*)&e0;
          const float* e1p = (const float*)&e1;
          const float* e2p = (const float*)&e2;
#pragma unroll
          for (int dd = 0; dd < 4; ++dd) {
            float v = __half2float(hp[dd]);
            if (reluf) v = fmaxf(fmaf(v, aA[dd], cC[dd]), 0.f);
            acc[dd] += fmaxf(v + e0p[dd] + e1p[dd] + e2p[dd], 0.f);
          }
        }
      }
      for (; i < cnt; i += 4) {  // tail: each quad one edge, predicated
        const int e = i + q;
        unsigned int pks = __shfl(mypk, (e < 64) ? e : 0);
        if (e < cnt) {
          uint2 hv = *(const uint2*)&src[(size_t)(pks & 0x1FFFFu) * 64 + d0];
          const __half* hp = (const __half*)&hv;
          const unsigned int b = pks >> 17;
          const float4 e0 = *(const float4*)&sb[(b & 7) * 64 + d0];
          const float4 e1 = *(const float4*)&sb[(((b >> 3) & 7) + 8) * 64 + d0];
          const float4 e2 = *(const float4*)&sb[((b >> 6) + 16) * 64 + d0];
          const float* e0p = (const float*)&e0;
          const float* e1p = (const float*)&e1;
          const float* e2p = (const float*)&e2;
#pragma unroll
          for (int dd = 0; dd < 4; ++dd) {
            float v = __half2float(hp[dd]);
            if (reluf) v = fmaxf(fmaf(v, aA[dd], cC[dd]), 0.f);
            acc[dd] += fmaxf(v + e0p[dd] + e1p[dd] + e2p[dd], 0.f);
          }
        }
      }
    }
#pragma unroll
    for (int dd = 0; dd < 4; ++dd) {
      acc[dd] += __shfl_xor(acc[dd], 16);
      acc[dd] += __shfl_xor(acc[dd], 32);
    }
    if (q == 0) {
      uint2 ow = *(const uint2*)&src[(size_t)n * 64 + d0];
      const __half* op = (const __half*)&ow;
      __half hv[4];
#pragma unroll
      for (int dd = 0; dd < 4; ++dd) {
        float o = __half2float(op[dd]);
        if (reluf) o = fmaxf(fmaf(o, aA[dd], cC[dd]), 0.f);
        hv[dd] = __float2half(fmaf(ep1, o, acc[dd]));
      }
      *(uint2*)&z[(size_t)n * 64 + d0] = *(uint2*)hv;
    }
  }
}

// ---------------- BN1 moments from z16: colsum, M = z^T z -------------------
__global__ void __launch_bounds__(256)
k_zstats(const __half* __restrict__ z, float* __restrict__ stats) {
  __shared__ __align__(16) float zl[2][64 * ZS];
  __shared__ float red[256];
  const int tid = threadIdx.x;
  const int wave = tid >> 6, d = tid & 63;
  const int ar = (tid >> 4) * 4, bc = (tid & 15) * 4;
  const int nr = tid >> 4, kc4 = (tid & 15) << 2;
  uint2 pf[4];

#define ZS_ISSUE(t)                                                           \
  {                                                                           \
    const int nb_ = (blockIdx.x * 4 + (t)) * 64;                              \
    const int nlim_ = N_NODES - nb_;                                          \
    _Pragma("unroll") for (int u = 0; u < 4; ++u) {                           \
      const int n_ = nr + u * 16;                                             \
      pf[u] = make_uint2(0u, 0u);                                             \
      if (n_ < nlim_) pf[u] = *(const uint2*)&z[(size_t)(nb_ + n_) * 64 + kc4]; \
    }                                                                         \
  }
#define ZS_STORE(buf)                                                         \
  {                                                                           \
    _Pragma("unroll") for (int u = 0; u < 4; ++u) {                           \
      const __half* hp_ = (const __half*)&pf[u];                              \
      float4 f_ = make_float4(__half2float(hp_[0]), __half2float(hp_[1]),     \
                              __half2float(hp_[2]), __half2float(hp_[3]));    \
      *(float4*)&zl[buf][(nr + u * 16) * ZS + kc4] = f_;                      \
    }                                                                         \
  }

  ZS_ISSUE(0);
  ZS_STORE(0);
  __syncthreads();

  float accS = 0.f;
  float m00 = 0.f, m01 = 0.f, m02 = 0.f, m03 = 0.f;
  float m10 = 0.f, m11 = 0.f, m12 = 0.f, m13 = 0.f;
  float m20 = 0.f, m21 = 0.f, m22 = 0.f, m23 = 0.f;
  float m30 = 0.f, m31 = 0.f, m32 = 0.f, m33 = 0.f;
  for (int t = 0; t < 4; ++t) {
    const int cur = t & 1;
    if (t < 3) ZS_ISSUE(t + 1);
#pragma unroll
    for (int ii = 0; ii < 16; ++ii) accS += zl[cur][(wave * 16 + ii) * ZS + d];
#pragma unroll 4
    for (int n = 0; n < 64; ++n) {
      const float4 a = *(const float4*)&zl[cur][n * ZS + ar];
      const float4 b = *(const float4*)&zl[cur][n * ZS + bc];
      m00 = fmaf(a.x, b.x, m00); m01 = fmaf(a.x, b.y, m01); m02 = fmaf(a.x, b.z, m02); m03 = fmaf(a.x, b.w, m03);
      m10 = fmaf(a.y, b.x, m10); m11 = fmaf(a.y, b.y, m11); m12 = fmaf(a.y, b.z, m12); m13 = fmaf(a.y, b.w, m13);
      m20 = fmaf(a.z, b.x, m20); m21 = fmaf(a.z, b.y, m21); m22 = fmaf(a.z, b.z, m22); m23 = fmaf(a.z, b.w, m23);
      m30 = fmaf(a.w, b.x, m30); m31 = fmaf(a.w, b.y, m31); m32 = fmaf(a.w, b.z, m32); m33 = fmaf(a.w, b.w, m33);
    }
    __syncthreads();
    if (t < 3) {
      ZS_STORE(cur ^ 1);
      __syncthreads();
    }
  }
  float* copy = stats + (blockIdx.x & 3) * 4160;  // [cs 64 | M 4096]
  red[tid] = accS;
  __syncthreads();
  if (tid < 64)
    atomicAdd(&copy[tid], red[tid] + red[tid + 64] + red[tid + 128] + red[tid + 192]);
  float* M = copy + 64;
  atomicAdd(&M[(ar + 0) * 64 + bc + 0], m00); atomicAdd(&M[(ar + 0) * 64 + bc + 1], m01);
  atomicAdd(&M[(ar + 0) * 64 + bc + 2], m02); atomicAdd(&M[(ar + 0) * 64 + bc + 3], m03);
  atomicAdd(&M[(ar + 1) * 64 + bc + 0], m10); atomicAdd(&M[(ar + 1) * 64 + bc + 1], m11);
  atomicAdd(&M[(ar + 1) * 64 + bc + 2], m12); atomicAdd(&M[(ar + 1) * 64 + bc + 3], m13);
  atomicAdd(&M[(ar + 2) * 64 + bc + 0], m20); atomicAdd(&M[(ar + 2) * 64 + bc + 1], m21);
  atomicAdd(&M[(ar + 2) * 64 + bc + 2], m22); atomicAdd(&M[(ar + 2) * 64 + bc + 3], m23);
  atomicAdd(&M[(ar + 3) * 64 + bc + 0], m30); atomicAdd(&M[(ar + 3) * 64 + bc + 1], m31);
  atomicAdd(&M[(ar + 3) * 64 + bc + 2], m32); atomicAdd(&M[(ar + 3) * 64 + bc + 3], m33);
#undef ZS_ISSUE
#undef ZS_STORE
}

// BN1 params + fp16 weight tables, parallel over 8 blocks. Block 0 zeroes
// s2/q2 (order: after pull reads them, before mm2 accumulates).
__global__ void __launch_bounds__(128)
k_fin1(const float* __restrict__ stats,
       const float* __restrict__ W1, const float* __restrict__ W2,
       const float* __restrict__ g1, const float* __restrict__ be1,
       float* __restrict__ a1, float* __restrict__ c1p,
       __half* __restrict__ w1t16, __half* __restrict__ w2t16,
       float* __restrict__ s2z, float* __restrict__ q2z) {
  __shared__ float Ml[4096];
  __shared__ float csl[64];
  const int tid = threadIdx.x, blk = blockIdx.x;
  if (blk == 0 && tid < 64) { s2z[tid] = 0.f; q2z[tid] = 0.f; }
  for (int i = tid; i < 4096; i += 128)
    Ml[i] = stats[64 + i] + stats[4160 + 64 + i] + stats[8320 + 64 + i] + stats[12480 + 64 + i];
  if (tid < 64) csl[tid] = stats[tid] + stats[4160 + tid] + stats[8320 + tid] + stats[12480 + tid];
  for (int i = blk * 1024 + tid; i < (blk + 1) * 1024; i += 128) {
    int k = i >> 6, jj = i & 63;
    w2t16[jj * 128 + k] = __float2half(W2[i]);
  }
  __syncthreads();
  const int j = blk * 16 + (tid >> 3), a = tid & 7;
  float wcol[64];
#pragma unroll
  for (int k = 0; k < 64; ++k) wcol[k] = W1[k * 128 + j];
#pragma unroll
  for (int kk = 0; kk < 8; ++kk)
    w1t16[j * 64 + a * 8 + kk] = __float2half(wcol[a * 8 + kk]);
  float m0 = 0.f;
#pragma unroll
  for (int kk = 0; kk < 8; ++kk)
    m0 = fmaf(csl[a * 8 + kk], wcol[a * 8 + kk], m0);
  float q = 0.f;
#pragma unroll
  for (int s = 0; s < 8; ++s) {
    const int ka = a + 8 * s;
    const float4* mr = (const float4*)&Ml[ka * 64];
    float t = 0.f;
#pragma unroll
    for (int kb = 0; kb < 16; ++kb) {
      float4 m = mr[kb];
      t = fmaf(m.x, wcol[kb * 4 + 0], t);
      t = fmaf(m.y, wcol[kb * 4 + 1], t);
      t = fmaf(m.z, wcol[kb * 4 + 2], t);
      t = fmaf(m.w, wcol[kb * 4 + 3], t);
    }
    q = fmaf(wcol[ka], t, q);
  }
  q += __shfl_xor(q, 1); q += __shfl_xor(q, 2); q += __shfl_xor(q, 4);
  m0 += __shfl_xor(m0, 1); m0 += __shfl_xor(m0, 2); m0 += __shfl_xor(m0, 4);
  if (a == 0) {
    m0 *= (1.0f / (float)N_NODES);
    float var = q * (1.0f / (float)N_NODES) - m0 * m0;
    float r = rsqrtf(var + 1e-5f);
    float A = g1[j] * r;
    a1[j] = A;
    c1p[j] = fmaf(-m0, A, be1[j]);
  }
}

// ---------------- fused MLP on MFMA (v_mfma_f32_16x16x32_f16) ---------------
__global__ void __launch_bounds__(256)
k_mm2(const __half* __restrict__ z16, const __half* __restrict__ w1t,
      const float* __restrict__ a1, const float* __restrict__ c1p,
      const __half* __restrict__ w2t, const float* __restrict__ b2,
      float* __restrict__ zout, __half* __restrict__ zout16, int tofp16,
      float* __restrict__ s2, float* __restrict__ q2) {
  __shared__ __align__(16) float sm[7040];           // 28.2 KB
  __half* z16l = (__half*)sm;                        // [64][72]
  __half* w1tl = (__half*)(sm + 2304);               // [128][72]
  __half* z1h = (__half*)sm;                         // [64][136] phase B overlay
  __half* w2tl = (__half*)(sm + 4352);               // [64][72]
  float* ss = sm + 6912;
  float* sq = sm + 6976;
  const int tid = threadIdx.x;
  const int nb = blockIdx.x * 64;
  const int nlim = N_NODES - nb;
  const int wv = tid >> 6, l = tid & 63;
  const int lrow = l & 15, lk = l >> 4;
  if (tid < 128) sm[6912 + tid] = 0.f;
  {
    int row = tid >> 2, seg = (tid & 3) * 16;
#pragma unroll
    for (int c = 0; c < 4; ++c) {
      uint2 v = make_uint2(0u, 0u);
      if (row < nlim) v = *(const uint2*)&z16[(size_t)(nb + row) * 64 + seg + c * 4];
      *(uint2*)&z16l[row * 72 + seg + c * 4] = v;
    }
  }
  {
    int row = tid >> 1, seg = (tid & 1) * 32;
#pragma unroll
    for (int c = 0; c < 8; ++c)
      *(uint2*)&w1tl[row * 72 + seg + c * 4] = *(const uint2*)&w1t[row * 64 + seg + c * 4];
  }
  __syncthreads();

  f32x4 acc[8];
#pragma unroll
  for (int jt = 0; jt < 8; ++jt) {
    f32x4 zr = {0.f, 0.f, 0.f, 0.f};
    acc[jt] = zr;
  }
  const f16x8 af0 = *(const f16x8*)&z16l[(16 * wv + lrow) * 72 + lk * 8];
  const f16x8 af1 = *(const f16x8*)&z16l[(16 * wv + lrow) * 72 + 32 + lk * 8];
#pragma unroll
  for (int jt = 0; jt < 8; ++jt) {
    const f16x8 b0 = *(const f16x8*)&w1tl[(lrow + 16 * jt) * 72 + lk * 8];
    const f16x8 b1 = *(const f16x8*)&w1tl[(lrow + 16 * jt) * 72 + 32 + lk * 8];
    acc[jt] = __builtin_amdgcn_mfma_f32_16x16x32_f16(af0, b0, acc[jt], 0, 0, 0);
    acc[jt] = __builtin_amdgcn_mfma_f32_16x16x32_f16(af1, b1, acc[jt], 0, 0, 0);
  }
  __syncthreads();  // z16l / w1tl reads complete; safe to overlay

#pragma unroll
  for (int jt = 0; jt < 8; ++jt) {
    const int col = lrow + 16 * jt;
    const float a = a1[col], cc = c1p[col];
#pragma unroll
    for (int r = 0; r < 4; ++r) {
      const int rl = 16 * wv + lk * 4 + r;
      float v = fmaxf(fmaf(acc[jt][r], a, cc), 0.f);
      z1h[rl * 136 + col] = __float2half(v);
    }
  }
  {
    int row = tid >> 2, seg = (tid & 3) * 16;
#pragma unroll
    for (int c = 0; c < 4; ++c)
      *(uint2*)&w2tl[row * 72 + seg + c * 4] = *(const uint2*)&w2t[row * 128 + seg + c * 4];
  }
  __syncthreads();

  f32x4 accB[4];
#pragma unroll
  for (int jt = 0; jt < 4; ++jt) {
    const float bb = b2[lrow + 16 * jt];
    f32x4 t = {bb, bb, bb, bb};
    accB[jt] = t;
  }
#pragma unroll
  for (int h = 0; h < 2; ++h) {
    if (h == 1) {
      __syncthreads();
      int row = tid >> 2, seg = (tid & 3) * 16;
#pragma unroll
      for (int c = 0; c < 4; ++c)
        *(uint2*)&w2tl[row * 72 + seg + c * 4] = *(const uint2*)&w2t[row * 128 + 64 + seg + c * 4];
      __syncthreads();
    }
#pragma unroll
    for (int kb = 0; kb < 2; ++kb) {
      const f16x8 afB = *(const f16x8*)&z1h[(16 * wv + lrow) * 136 + h * 64 + kb * 32 + lk * 8];
#pragma unroll
      for (int jt = 0; jt < 4; ++jt) {
        const f16x8 bfB = *(const f16x8*)&w2tl[(lrow + 16 * jt) * 72 + kb * 32 + lk * 8];
        accB[jt] = __builtin_amdgcn_mfma_f32_16x16x32_f16(afB, bfB, accB[jt], 0, 0, 0);
      }
    }
  }
  // epilogue: write z2 (fp16 l<3 / fp32 l=3) + stats
#pragma unroll
  for (int jt = 0; jt < 4; ++jt) {
    const int col = lrow + 16 * jt;
    float s = 0.f, q = 0.f;
#pragma unroll
    for (int r = 0; r < 4; ++r) {
      const int rl = 16 * wv + lk * 4 + r;
      if (rl < nlim) {
        const float v = accB[jt][r];
        if (tofp16) zout16[(size_t)(nb + rl) * 64 + col] = __float2half(v);
        else zout[(size_t)(nb + rl) * 64 + col] = v;
        s += v;
        q = fmaf(v, v, q);
      }
    }
    atomicAdd(&ss[col], s);
    atomicAdd(&sq[col], q);
  }
  __syncthreads();
  if (tid < 64) {
    atomicAdd(&s2[tid], ss[tid]);
    atomicAdd(&q2[tid], sq[tid]);
  }
}

// ---------------- pool: batch sorted; per-lane BN2 affine; zero atomics ----
__global__ void __launch_bounds__(256)
k_pool(const float* __restrict__ z2, const float* __restrict__ s2p,
       const float* __restrict__ q2p, const float* __restrict__ bng,
       const float* __restrict__ bnb, const int* __restrict__ batch,
       float* __restrict__ out) {
  int g = blockIdx.x * 4 + (threadIdx.x >> 6);
  int d = threadIdx.x & 63;
  const float inv = 1.0f / (float)N_NODES;
  float m = s2p[d] * inv;
  float vv = q2p[d] * inv - m * m;
  float r = rsqrtf(vv + 1e-5f);
  float a2 = bng[d] * r;
  float c2 = fmaf(-m, a2, bnb[d]);
  int a = 0, b = N_NODES;
  while (a < b) { int mm = (a + b) >> 1; if (batch[mm] < g) a = mm + 1; else b = mm; }
  const int lo = a;
  b = N_NODES;
  while (a < b) { int mm = (a + b) >> 1; if (batch[mm] < g + 1) a = mm + 1; else b = mm; }
  const int hi = a;
  float s0 = 0.f, s1 = 0.f, s2r = 0.f, s3 = 0.f;
  int n = lo;
  for (; n + 4 <= hi; n += 4) {
    s0 += z2[(size_t)(n + 0) * 64 + d];
    s1 += z2[(size_t)(n + 1) * 64 + d];
    s2r += z2[(size_t)(n + 2) * 64 + d];
    s3 += z2[(size_t)(n + 3) * 64 + d];
  }
  for (; n < hi; ++n) s0 += z2[(size_t)n * 64 + d];
  float S = (s0 + s1) + (s2r + s3);
  float cntf = (float)(hi - lo);
  out[g * 64 + d] = fmaf(S, a2, cntf * c2) / (cntf + 1e-9f);
}

extern "C" void kernel_launch(void* const* d_in, const int* in_sizes, int n_in,
                              void* d_out, int out_size, void* d_ws, size_t ws_size,
                              hipStream_t stream) {
  const int* x = (const int*)d_in[0];
  const int* ea = (const int*)d_in[1];
  const int* ei = (const int*)d_in[2];
  const int* batch = (const int*)d_in[3];
  const float* atom_emb = (const float*)d_in[4];
  const float* bond_emb = (const float*)d_in[5];
  const float* W1 = (const float*)d_in[6];
  const float* g1 = (const float*)d_in[8];
  const float* be1 = (const float*)d_in[9];
  const float* W2 = (const float*)d_in[10];
  const float* b2 = (const float*)d_in[11];
  const float* eps = (const float*)d_in[12];
  const float* bn_g = (const float*)d_in[13];
  const float* bn_b = (const float*)d_in[14];

  float* w = (float*)d_ws;
  float* A = w;                                 // fp32 z2 (layer 3 only)
  __half* A16 = (__half*)w;                     // row-major fp16 mirror
  float* B = w + (size_t)N_NODES * 64;
  __half* B16 = (__half*)B;
  float* stats = B + (size_t)N_NODES * 64;      // 4x(cs|M) = 16640
  float* s2 = stats + 16640;
  float* q2 = stats + 16704;
  float* a1 = stats + 16768;
  float* c1p = stats + 16896;
  __half* w1t16 = (__half*)(stats + 17024);     // 8192 halves
  __half* w2t16 = (__half*)(stats + 21120);     // 8192 halves
  int* ptr = (int*)(stats + 25216);             // 100001
  int* deg = ptr + (N_NODES + 1);               // 100000
  unsigned int* csr = (unsigned int*)(deg + N_NODES);  // 1.6M
  int* bs = (int*)(csr + N_EDGES);              // 391

  const int NBLK = (N_NODES + 255) / 256;   // 391
  const int NTILE = (N_NODES + 63) / 64;    // 1563
  const int NPULL = N_NODES / 32;           // 3125 (exact)
  const int NZ = NBLK;                      // 391

  hipMemsetAsync(deg, 0, N_NODES * sizeof(int), stream);

  k_atom_embed<<<N_NODES / 4, 256, 0, stream>>>(x, atom_emb, A16);

  // CSR build (once; reused across all 4 layers)
  k_hist<<<(N_EDGES + 255) / 256, 256, 0, stream>>>(ei, deg);
  k_scan1<<<NBLK, 256, 0, stream>>>(deg, bs);
  k_scan2<<<1, 512, 0, stream>>>(bs, NBLK);
  k_scan3<<<NBLK, 256, 0, stream>>>(deg, bs, ptr);
  k_fill<<<(N_EDGES + 255) / 256, 256, 0, stream>>>(ei, ea, deg, csr);

  for (int l = 0; l < NL; ++l) {
    k_pull<<<NPULL, 256, 0, stream>>>(
        A16, csr, ptr, bond_emb + (size_t)l * 1536, s2, q2,
        bn_g + (l > 0 ? (l - 1) * 64 : 0), bn_b + (l > 0 ? (l - 1) * 64 : 0),
        eps + l, (l > 0) ? 1 : 0, B16, stats);
    k_zstats<<<NZ, 256, 0, stream>>>(B16, stats);
    k_fin1<<<8, 128, 0, stream>>>(stats, W1 + (size_t)l * 8192, W2 + (size_t)l * 8192,
                                  g1 + l * 128, be1 + l * 128, a1, c1p, w1t16, w2t16,
                                  s2, q2);
    k_mm2<<<NTILE, 256, 0, stream>>>(
        B16, w1t16, a1, c1p, w2t16, b2 + l * 64,
        A, A16, (l < NL - 1) ? 1 : 0, s2, q2);
  }
  k_pool<<<NG / 4, 256, 0, stream>>>(A, s2, q2, bn_g + 3 * 64, bn_b + 3 * 64,
                                     batch, (float*)d_out);
}